// Round 3
// baseline (101.589 us; speedup 1.0000x reference)
//
#include <hip/hip_runtime.h>

#define HH 1024
#define WW 1024
#define NPIX (HH*WW)
#define NRB 64          // rowblocks per sample (16 rows each)
#define EPSF 1e-8f

__device__ inline float wrsum(float v){ for(int o=32;o;o>>=1) v += __shfl_down(v,o); return v; }
__device__ inline float wrmin(float v){ for(int o=32;o;o>>=1) v = fminf(v,__shfl_down(v,o)); return v; }
__device__ inline float wrmax(float v){ for(int o=32;o;o>>=1) v = fmaxf(v,__shfl_down(v,o)); return v; }

// ---- Kernel 1 (the ONLY full-data pass) ----
// Block = (sample s, rowblock rb of 16 rows). Thread t owns cols 4t..4t+3.
__global__ __launch_bounds__(256) void k_main(const float* __restrict__ x,
    float* __restrict__ CSx, float* __restrict__ CMin, float* __restrict__ CMax,
    float* __restrict__ RM, float* __restrict__ p1){
  int s = blockIdx.x >> 6, rb = blockIdx.x & 63;
  int t = threadIdx.x;
  const float4* xp = (const float4*)(x + (size_t)s*NPIX + (size_t)rb*16*WW);
  float sabs=0.f, cnt=0.f, sxx=0.f;
  float cmin[4]={INFINITY,INFINITY,INFINITY,INFINITY};
  float cmax[4]={-INFINITY,-INFINITY,-INFINITY,-INFINITY};
  float csum[4]={0.f,0.f,0.f,0.f};
  float rm[16];
  #pragma unroll
  for(int r=0;r<16;r++){
    float4 v = xp[r*256 + t];
    float a[4]={v.x,v.y,v.z,v.w};
    float rmx = -INFINITY;
    #pragma unroll
    for(int j=0;j<4;j++){
      float xx = a[j];
      rmx = fmaxf(rmx, xx);
      cmin[j] = fminf(cmin[j], xx);
      cmax[j] = fmaxf(cmax[j], xx);
      csum[j] += xx;
      sxx = fmaf(xx, xx, sxx);
      // |sigmoid(x)-0.5| = 0.5 - 1/(1+e^{|x|}) ; native v_exp path
      float e = __expf(fabsf(xx));
      sabs += 0.5f - 1.f/(1.f + e);
      cnt += (xx > 0.f) ? 1.f : 0.f;   // sigmoid(x)>0.5 <=> x>0
    }
    rm[r] = rmx;
  }
  size_t cbase = ((size_t)s*NRB + rb)*WW + 4*t;
  *(float4*)(CSx  + cbase) = make_float4(csum[0],csum[1],csum[2],csum[3]);
  *(float4*)(CMin + cbase) = make_float4(cmin[0],cmin[1],cmin[2],cmin[3]);
  *(float4*)(CMax + cbase) = make_float4(cmax[0],cmax[1],cmax[2],cmax[3]);

  float vmin = fminf(fminf(cmin[0],cmin[1]), fminf(cmin[2],cmin[3]));
  float vmax = fmaxf(fmaxf(cmax[0],cmax[1]), fmaxf(cmax[2],cmax[3]));
  float sx   = csum[0]+csum[1]+csum[2]+csum[3];
  vmin = wrmin(vmin); vmax = wrmax(vmax);
  sabs = wrsum(sabs); cnt = wrsum(cnt); sx = wrsum(sx); sxx = wrsum(sxx);

  __shared__ float sred[6][4];
  __shared__ float rowls[4][16];
  int wid = t>>6, lane = t&63;
  if(lane==0){ sred[0][wid]=vmin; sred[1][wid]=vmax; sred[2][wid]=sabs;
               sred[3][wid]=cnt;  sred[4][wid]=sx;   sred[5][wid]=sxx; }
  #pragma unroll
  for(int r=0;r<16;r++){
    float m = wrmax(rm[r]);
    if(lane==0) rowls[wid][r] = m;
  }
  __syncthreads();
  if(t<16)
    RM[(size_t)s*HH + rb*16 + t] =
      fmaxf(fmaxf(rowls[0][t],rowls[1][t]), fmaxf(rowls[2][t],rowls[3][t]));
  if(t==0){
    float* o = p1 + ((size_t)s*NRB + rb)*8;
    o[0] = fminf(fminf(sred[0][0],sred[0][1]), fminf(sred[0][2],sred[0][3]));
    o[1] = fmaxf(fmaxf(sred[1][0],sred[1][1]), fmaxf(sred[1][2],sred[1][3]));
    o[2] = sred[2][0]+sred[2][1]+sred[2][2]+sred[2][3];
    o[3] = sred[3][0]+sred[3][1]+sred[3][2]+sred[3][3];
    o[4] = sred[4][0]+sred[4][1]+sred[4][2]+sred[4][3];
    o[5] = sred[5][0]+sred[5][1]+sred[5][2]+sred[5][3];
  }
}

// ---- Kernel 2: per-sample stats + rect bounds; also zeroes the done-counter ----
__global__ __launch_bounds__(256) void k_rect(const float* __restrict__ p1,
    const float* __restrict__ RM, const float* __restrict__ CMax,
    int* __restrict__ rectI, float* __restrict__ rectF, int* __restrict__ counter){
  int s = blockIdx.x, t = threadIdx.x;
  if(s==0 && t==0) *counter = 0;
  __shared__ float bc[8];
  __shared__ int ext[4];          // r0min, r1max, c0min, c1max
  if(t==0){ ext[0]=0x7fffffff; ext[1]=-1; ext[2]=0x7fffffff; ext[3]=-1; }
  if(t<64){
    const float* o = p1 + ((size_t)s*NRB + t)*8;
    float m=o[0], M=o[1], S=o[2], C=o[3], X=o[4], XX=o[5];
    m=wrmin(m); M=wrmax(M); S=wrsum(S); C=wrsum(C); X=wrsum(X); XX=wrsum(XX);
    if(t==0){
      float lo=m, d=M-m+EPSF, inv=1.f/d, T=lo+0.5f*d;
      float conf = S/(float)NPIX, area = C/(float)NPIX;
      float w = 0.4f;
      if(conf < 0.3f)  w *= 2.0f;
      if(area < 0.05f) w *= 1.5f;
      if(conf > 0.4f && area > 0.1f) w *= 0.5f;
      float sumpn2 = inv*inv*(XX - 2.f*lo*X + (float)NPIX*lo*lo);
      bc[0]=lo; bc[1]=inv; bc[2]=T; bc[3]=w; bc[4]=sumpn2;
    }
  }
  __syncthreads();
  float T = bc[2];
  { // row extents: 4 rows per thread
    int rlo=0x7fffffff, rhi=-1;
    #pragma unroll
    for(int i=0;i<4;i++){
      int r = t*4+i;
      if(RM[(size_t)s*HH + r] > T){ rlo = min(rlo,r); rhi = max(rhi,r); }
    }
    if(rhi>=0){ atomicMin(&ext[0],rlo); atomicMax(&ext[1],rhi); }
  }
  { // col extents: reduce CMax over 64 rowblocks, 4 cols per thread
    const float4* cm = (const float4*)(CMax + (size_t)s*NRB*WW) + t;
    float4 mx = cm[0];
    #pragma unroll 4
    for(int rb=1; rb<NRB; rb++){
      float4 v = cm[rb*256];
      mx.x=fmaxf(mx.x,v.x); mx.y=fmaxf(mx.y,v.y);
      mx.z=fmaxf(mx.z,v.z); mx.w=fmaxf(mx.w,v.w);
    }
    float a[4]={mx.x,mx.y,mx.z,mx.w};
    int clo=0x7fffffff, chi=-1;
    #pragma unroll
    for(int j=0;j<4;j++) if(a[j] > T){ int c=4*t+j; clo=min(clo,c); chi=max(chi,c); }
    if(chi>=0){ atomicMin(&ext[2],clo); atomicMax(&ext[3],chi); }
  }
  __syncthreads();
  if(t==0){
    int anyb = (ext[1] >= 0);
    rectI[s*4+0] = anyb ? ext[0] : -1;
    rectI[s*4+1] = ext[1];
    rectI[s*4+2] = anyb ? ext[2] : -1;
    rectI[s*4+3] = ext[3];
    rectF[s*8+0]=bc[0]; rectF[s*8+1]=bc[1]; rectF[s*8+2]=bc[2];
    rectF[s*8+3]=bc[3]; rectF[s*8+4]=bc[4];
  }
}

// ---- Kernel 3: rect sum/min from summaries (+boundary rows); last block finalizes ----
__global__ __launch_bounds__(256) void k_rest(const float* __restrict__ x,
    const float* __restrict__ CSx, const float* __restrict__ CMin,
    const int* __restrict__ rectI, const float* __restrict__ rectF,
    float* __restrict__ p3, int* __restrict__ counter, float* __restrict__ out, int B){
  int s = blockIdx.x >> 3, chunk = blockIdx.x & 7;
  int t = threadIdx.x;
  int r0=rectI[s*4], r1=rectI[s*4+1], c0=rectI[s*4+2], c1=rectI[s*4+3];
  float sum=0.f, mn=INFINITY;
  if(r0 >= 0){
    for(int rb=chunk*8; rb<chunk*8+8; rb++){
      int ra=rb*16, rz=ra+15;
      bool full = (ra >= r0) && (rz <= r1);
      if(full){
        const float* cs = CSx  + ((size_t)s*NRB + rb)*WW;
        const float* cm = CMin + ((size_t)s*NRB + rb)*WW;
        for(int c=c0+t; c<=c1; c+=256){ sum += cs[c]; mn = fminf(mn, cm[c]); }
      } else if(rz >= r0 && ra <= r1){
        int pa = max(ra,r0), pb = min(rz,r1);
        for(int r=pa; r<=pb; r++){
          const float* xr = x + (size_t)s*NPIX + (size_t)r*WW;
          for(int c=c0+t; c<=c1; c+=256){ float v=xr[c]; sum += v; mn = fminf(mn,v); }
        }
      }
    }
  }
  sum = wrsum(sum); mn = wrmin(mn);
  __shared__ float l1[4], l2[4];
  int wid=t>>6, lane=t&63;
  if(lane==0){ l1[wid]=sum; l2[wid]=mn; }
  __syncthreads();
  if(t==0){
    p3[(s*8+chunk)*2+0] = l1[0]+l1[1]+l1[2]+l1[3];
    p3[(s*8+chunk)*2+1] = fminf(fminf(l2[0],l2[1]), fminf(l2[2],l2[3]));
  }

  // ---- last-block-done final reduction ----
  __shared__ int lastFlag;
  __threadfence();
  if(t==0){
    int old = atomicAdd(counter, 1);
    lastFlag = (old == (int)gridDim.x - 1);
  }
  __syncthreads();
  if(!lastFlag) return;
  __threadfence();
  __shared__ float lossS[32], valS[32];
  int ss = t>>3, k = t&7;
  float su=0.f, mi=INFINITY;
  if(ss < B){ su = p3[(ss*8+k)*2]; mi = p3[(ss*8+k)*2+1]; }
  for(int o=4;o;o>>=1){ su += __shfl_down(su,o,8); mi = fminf(mi,__shfl_down(mi,o,8)); }
  if(ss < B && k==0){
    int rr0=rectI[ss*4], rr1=rectI[ss*4+1], cc0=rectI[ss*4+2], cc1=rectI[ss*4+3];
    float lo=rectF[ss*8], inv=rectF[ss*8+1], T=rectF[ss*8+2], w=rectF[ss*8+3], spn2=rectF[ss*8+4];
    float loss=0.f, val=0.f;
    if(rr0 >= 0){
      float area = (float)((rr1-rr0+1)*(cc1-cc0+1));
      val = (mi <= T) ? 1.f : 0.f;
      float srpn = inv*(su - area*lo);
      float base = (spn2 - 2.f*srpn + area)/(float)NPIX;
      loss = base * w * val;
    }
    lossS[ss]=loss; valS[ss]=val;
  }
  __syncthreads();
  if(t < 32){
    float l = (t<B)?lossS[t]:0.f, v = (t<B)?valS[t]:0.f;
    for(int o=16;o;o>>=1){ l += __shfl_down(l,o,32); v += __shfl_down(v,o,32); }
    if(t==0) out[0] = (v > 0.f) ? (l / fmaxf(v,1.f)) : 0.f;
  }
}

extern "C" void kernel_launch(void* const* d_in, const int* in_sizes, int n_in,
                              void* d_out, int out_size, void* d_ws, size_t ws_size,
                              hipStream_t stream) {
  const float* x = (const float*)d_in[0];
  int B = in_sizes[0] / NPIX;   // 32
  char* ws = (char*)d_ws;
  float* CSx  = (float*)(ws);                                   // 8 MB
  float* CMin = (float*)(ws + (size_t)8*1024*1024);             // 8 MB
  float* CMax = (float*)(ws + (size_t)16*1024*1024);            // 8 MB
  float* RM   = (float*)(ws + (size_t)24*1024*1024);            // 128 KB
  float* p1   = (float*)(ws + (size_t)24*1024*1024 + 131072);   // 64 KB
  int*   rectI= (int*)  (ws + (size_t)24*1024*1024 + 196608);   // 512 B (pad 4K)
  float* rectF= (float*)(ws + (size_t)24*1024*1024 + 200704);   // 1 KB (pad 4K)
  float* p3   = (float*)(ws + (size_t)24*1024*1024 + 204800);   // 2 KB (pad 4K)
  int*   ctr  = (int*)  (ws + (size_t)24*1024*1024 + 208896);   // 4 B
  float* out  = (float*)d_out;

  k_main<<<B*NRB, 256, 0, stream>>>(x, CSx, CMin, CMax, RM, p1);
  k_rect<<<B,     256, 0, stream>>>(p1, RM, CMax, rectI, rectF, ctr);
  k_rest<<<B*8,   256, 0, stream>>>(x, CSx, CMin, rectI, rectF, p3, ctr, out, B);
}

// Round 4
// 98.231 us; speedup vs baseline: 1.0342x; 1.0342x over previous
//
#include <hip/hip_runtime.h>

#define HH 1024
#define WW 1024
#define NPIX (HH*WW)
#define NRB 64          // rowblocks per sample (16 rows each)
#define EPSF 1e-8f
#define AGENT __HIP_MEMORY_SCOPE_AGENT

__device__ inline float wrsum(float v){ for(int o=32;o;o>>=1) v += __shfl_down(v,o); return v; }
__device__ inline float wrmin(float v){ for(int o=32;o;o>>=1) v = fminf(v,__shfl_down(v,o)); return v; }
__device__ inline float wrmax(float v){ for(int o=32;o;o>>=1) v = fmaxf(v,__shfl_down(v,o)); return v; }

// ---- Kernel 1 (the ONLY full-data pass) ----
// Block = (sample s, rowblock rb of 16 rows). Thread t owns cols 4t..4t+3.
// Also initializes rect extents + counters for kernel 2 (stream order guarantees visibility).
__global__ __launch_bounds__(256) void k_main(const float* __restrict__ x,
    float* __restrict__ CSx, float* __restrict__ CMin, float* __restrict__ CMax,
    float* __restrict__ RM, float* __restrict__ p1,
    int* __restrict__ rectI, int* __restrict__ ctrA, int* __restrict__ ctrB,
    int* __restrict__ ctrG){
  int s = blockIdx.x >> 6, rb = blockIdx.x & 63;
  int t = threadIdx.x;
  if(rb==0 && t==0){
    rectI[s*4+0]=0x7fffffff; rectI[s*4+1]=-1;
    rectI[s*4+2]=0x7fffffff; rectI[s*4+3]=-1;
    ctrA[s]=0; ctrB[s]=0;
    if(s==0) *ctrG = 0;
  }
  const float4* xp = (const float4*)(x + (size_t)s*NPIX + (size_t)rb*16*WW);
  float sabs=0.f, cnt=0.f, sxx=0.f;
  float cmin[4]={INFINITY,INFINITY,INFINITY,INFINITY};
  float cmax[4]={-INFINITY,-INFINITY,-INFINITY,-INFINITY};
  float csum[4]={0.f,0.f,0.f,0.f};
  float rm[16];
  #pragma unroll
  for(int r=0;r<16;r++){
    float4 v = xp[r*256 + t];
    float a[4]={v.x,v.y,v.z,v.w};
    float rmx = -INFINITY;
    #pragma unroll
    for(int j=0;j<4;j++){
      float xx = a[j];
      rmx = fmaxf(rmx, xx);
      cmin[j] = fminf(cmin[j], xx);
      cmax[j] = fmaxf(cmax[j], xx);
      csum[j] += xx;
      sxx = fmaf(xx, xx, sxx);
      float e = __expf(fabsf(xx));          // |sigmoid(x)-0.5| = 0.5 - 1/(1+e^{|x|})
      sabs += 0.5f - 1.f/(1.f + e);
      cnt += (xx > 0.f) ? 1.f : 0.f;        // sigmoid(x)>0.5 <=> x>0
    }
    rm[r] = rmx;
  }
  size_t cbase = ((size_t)s*NRB + rb)*WW + 4*t;
  *(float4*)(CSx  + cbase) = make_float4(csum[0],csum[1],csum[2],csum[3]);
  *(float4*)(CMin + cbase) = make_float4(cmin[0],cmin[1],cmin[2],cmin[3]);
  *(float4*)(CMax + cbase) = make_float4(cmax[0],cmax[1],cmax[2],cmax[3]);

  float vmin = fminf(fminf(cmin[0],cmin[1]), fminf(cmin[2],cmin[3]));
  float vmax = fmaxf(fmaxf(cmax[0],cmax[1]), fmaxf(cmax[2],cmax[3]));
  float sx   = csum[0]+csum[1]+csum[2]+csum[3];
  vmin = wrmin(vmin); vmax = wrmax(vmax);
  sabs = wrsum(sabs); cnt = wrsum(cnt); sx = wrsum(sx); sxx = wrsum(sxx);

  __shared__ float sred[6][4];
  __shared__ float rowls[4][16];
  int wid = t>>6, lane = t&63;
  if(lane==0){ sred[0][wid]=vmin; sred[1][wid]=vmax; sred[2][wid]=sabs;
               sred[3][wid]=cnt;  sred[4][wid]=sx;   sred[5][wid]=sxx; }
  #pragma unroll
  for(int r=0;r<16;r++){
    float m = wrmax(rm[r]);
    if(lane==0) rowls[wid][r] = m;
  }
  __syncthreads();
  if(t<16)
    RM[(size_t)s*HH + rb*16 + t] =
      fmaxf(fmaxf(rowls[0][t],rowls[1][t]), fmaxf(rowls[2][t],rowls[3][t]));
  if(t==0){
    float* o = p1 + ((size_t)s*NRB + rb)*8;
    o[0] = fminf(fminf(sred[0][0],sred[0][1]), fminf(sred[0][2],sred[0][3]));
    o[1] = fmaxf(fmaxf(sred[1][0],sred[1][1]), fmaxf(sred[1][2],sred[1][3]));
    o[2] = sred[2][0]+sred[2][1]+sred[2][2]+sred[2][3];
    o[3] = sred[3][0]+sred[3][1]+sred[3][2]+sred[3][3];
    o[4] = sred[4][0]+sred[4][1]+sred[4][2]+sred[4][3];
    o[5] = sred[5][0]+sred[5][1]+sred[5][2]+sred[5][3];
  }
}

// ---- Kernel 2: everything else. 8 blocks per sample, per-sample spin sync. ----
// Grid = B*8 = 256 blocks <= 256 CUs -> all co-resident, spin is deadlock-free.
__global__ __launch_bounds__(256) void k_rest(const float* __restrict__ x,
    const float* __restrict__ CSx, const float* __restrict__ CMin,
    const float* __restrict__ CMax, const float* __restrict__ RM,
    const float* __restrict__ p1, int* __restrict__ rectI,
    int* __restrict__ ctrA, int* __restrict__ ctrB, int* __restrict__ ctrG,
    float* __restrict__ p3, float* __restrict__ lossV, float* __restrict__ valV,
    float* __restrict__ out, int B){
  int s = blockIdx.x >> 3, k = blockIdx.x & 7;
  int t = threadIdx.x;
  __shared__ float bc[5];
  // A: per-sample scalar stats (wave 0 only; redundantly in all 8 blocks)
  if(t < 64){
    const float* o = p1 + ((size_t)s*NRB + t)*8;
    float m=o[0], M=o[1], S=o[2], C=o[3], X=o[4], XX=o[5];
    m=wrmin(m); M=wrmax(M); S=wrsum(S); C=wrsum(C); X=wrsum(X); XX=wrsum(XX);
    if(t==0){
      float lo=m, d=M-m+EPSF, inv=1.f/d;
      float conf = S/(float)NPIX, area = C/(float)NPIX;
      float w = 0.4f;
      if(conf < 0.3f)  w *= 2.0f;
      if(area < 0.05f) w *= 1.5f;
      if(conf > 0.4f && area > 0.1f) w *= 0.5f;
      bc[0]=lo; bc[1]=inv; bc[2]=lo+0.5f*d; bc[3]=w;
      bc[4]=inv*inv*(XX - 2.f*lo*X + (float)NPIX*lo*lo);
    }
  }
  __shared__ int ext[4];
  if(t==0){ ext[0]=0x7fffffff; ext[1]=-1; ext[2]=0x7fffffff; ext[3]=-1; }
  __syncthreads();
  float lo=bc[0], inv=bc[1], T=bc[2], w=bc[3], spn2=bc[4];
  // B: extents. This block owns 128 columns; block k==0 also does rows.
  if(t < 128){
    int c = (k<<7) + t;
    const float* cm = CMax + (size_t)s*NRB*WW + c;
    float mx = -INFINITY;
    #pragma unroll 8
    for(int rb=0; rb<NRB; rb++) mx = fmaxf(mx, cm[(size_t)rb*WW]);
    if(mx > T){ atomicMin(&ext[2], c); atomicMax(&ext[3], c); }
  }
  if(k==0){
    int rlo=0x7fffffff, rhi=-1;
    #pragma unroll
    for(int i=0;i<4;i++){
      int r=(t<<2)+i;
      if(RM[(size_t)s*HH + r] > T){ rlo=min(rlo,r); rhi=max(rhi,r); }
    }
    if(rhi>=0){ atomicMin(&ext[0],rlo); atomicMax(&ext[1],rhi); }
  }
  __syncthreads();
  if(t==0){
    if(ext[3]>=0){ atomicMin(&rectI[s*4+2],ext[2]); atomicMax(&rectI[s*4+3],ext[3]); }
    if(k==0 && ext[1]>=0){ atomicMin(&rectI[s*4+0],ext[0]); atomicMax(&rectI[s*4+1],ext[1]); }
    __threadfence();
    __hip_atomic_fetch_add(&ctrA[s], 1, __ATOMIC_RELEASE, AGENT);
    while(__hip_atomic_load(&ctrA[s], __ATOMIC_ACQUIRE, AGENT) < 8)
      __builtin_amdgcn_s_sleep(8);
    ext[0]=__hip_atomic_load(&rectI[s*4+0], __ATOMIC_RELAXED, AGENT);
    ext[1]=__hip_atomic_load(&rectI[s*4+1], __ATOMIC_RELAXED, AGENT);
    ext[2]=__hip_atomic_load(&rectI[s*4+2], __ATOMIC_RELAXED, AGENT);
    ext[3]=__hip_atomic_load(&rectI[s*4+3], __ATOMIC_RELAXED, AGENT);
  }
  __syncthreads();
  int r0=ext[0], r1=ext[1], c0=ext[2], c1=ext[3];
  // C: rect sum/min over this block's 8 rowblocks (summaries + boundary rows)
  float sum=0.f, mn=INFINITY;
  if(r1 >= 0){
    for(int rb=k*8; rb<k*8+8; rb++){
      int ra=rb*16, rz=ra+15;
      bool full = (ra >= r0) && (rz <= r1);
      if(full){
        const float* cs = CSx  + ((size_t)s*NRB + rb)*WW;
        const float* cm = CMin + ((size_t)s*NRB + rb)*WW;
        for(int c=c0+t; c<=c1; c+=256){ sum += cs[c]; mn = fminf(mn, cm[c]); }
      } else if(rz >= r0 && ra <= r1){
        int pa = max(ra,r0), pb = min(rz,r1);
        for(int r=pa; r<=pb; r++){
          const float* xr = x + (size_t)s*NPIX + (size_t)r*WW;
          for(int c=c0+t; c<=c1; c+=256){ float v=xr[c]; sum += v; mn = fminf(mn,v); }
        }
      }
    }
  }
  sum = wrsum(sum); mn = wrmin(mn);
  __shared__ float l1[4], l2[4];
  int wid=t>>6, lane=t&63;
  if(lane==0){ l1[wid]=sum; l2[wid]=mn; }
  __syncthreads();
  if(t==0){
    float bs = l1[0]+l1[1]+l1[2]+l1[3];
    float bm = fminf(fminf(l2[0],l2[1]), fminf(l2[2],l2[3]));
    __hip_atomic_store(&p3[((size_t)s*8+k)*2+0], bs, __ATOMIC_RELAXED, AGENT);
    __hip_atomic_store(&p3[((size_t)s*8+k)*2+1], bm, __ATOMIC_RELAXED, AGENT);
    int old = __hip_atomic_fetch_add(&ctrB[s], 1, __ATOMIC_ACQ_REL, AGENT);
    if(old == 7){
      // D: per-sample finalize (fixed index order -> deterministic)
      float su=0.f, mi=INFINITY;
      for(int j=0;j<8;j++){
        su +=            __hip_atomic_load(&p3[((size_t)s*8+j)*2+0], __ATOMIC_RELAXED, AGENT);
        mi = fminf(mi,   __hip_atomic_load(&p3[((size_t)s*8+j)*2+1], __ATOMIC_RELAXED, AGENT));
      }
      float loss=0.f, val=0.f;
      if(r1 >= 0){
        float area = (float)((r1-r0+1)*(c1-c0+1));
        val = (mi <= T) ? 1.f : 0.f;          // exists rect pixel not binary
        float srpn = inv*(su - area*lo);      // sum of pn over rect
        loss = ((spn2 - 2.f*srpn + area)/(float)NPIX) * w * val;
      }
      __hip_atomic_store(&lossV[s], loss, __ATOMIC_RELAXED, AGENT);
      __hip_atomic_store(&valV[s],  val,  __ATOMIC_RELAXED, AGENT);
      int o2 = __hip_atomic_fetch_add(ctrG, 1, __ATOMIC_ACQ_REL, AGENT);
      if(o2 == B-1){
        // E: global finalize (fixed order -> deterministic)
        float L=0.f, V=0.f;
        for(int ss=0; ss<B; ss++){
          L += __hip_atomic_load(&lossV[ss], __ATOMIC_RELAXED, AGENT);
          V += __hip_atomic_load(&valV[ss],  __ATOMIC_RELAXED, AGENT);
        }
        out[0] = (V > 0.f) ? (L / fmaxf(V, 1.f)) : 0.f;
      }
    }
  }
}

extern "C" void kernel_launch(void* const* d_in, const int* in_sizes, int n_in,
                              void* d_out, int out_size, void* d_ws, size_t ws_size,
                              hipStream_t stream) {
  const float* x = (const float*)d_in[0];
  int B = in_sizes[0] / NPIX;   // 32
  char* ws = (char*)d_ws;
  float* CSx  = (float*)(ws);                                   // 8 MB
  float* CMin = (float*)(ws + (size_t) 8*1024*1024);            // 8 MB
  float* CMax = (float*)(ws + (size_t)16*1024*1024);            // 8 MB
  float* RM   = (float*)(ws + (size_t)24*1024*1024);            // 128 KB
  float* p1   = (float*)(ws + (size_t)24*1024*1024 + 131072);   // 64 KB
  char*  b2   =          ws + (size_t)24*1024*1024 + 196608;
  int*   rectI= (int*)  (b2 + 0);      // 512 B
  int*   ctrA = (int*)  (b2 + 1024);   // 128 B
  int*   ctrB = (int*)  (b2 + 2048);   // 128 B
  int*   ctrG = (int*)  (b2 + 3072);   // 4 B
  float* p3   = (float*)(b2 + 4096);   // 2 KB
  float* lossV= (float*)(b2 + 8192);   // 128 B
  float* valV = (float*)(b2 + 8320);   // 128 B
  float* out  = (float*)d_out;

  k_main<<<B*NRB, 256, 0, stream>>>(x, CSx, CMin, CMax, RM, p1, rectI, ctrA, ctrB, ctrG);
  k_rest<<<B*8,   256, 0, stream>>>(x, CSx, CMin, CMax, RM, p1, rectI, ctrA, ctrB, ctrG,
                                    p3, lossV, valV, out, B);
}

// Round 5
// 66.751 us; speedup vs baseline: 1.5219x; 1.4716x over previous
//
#include <hip/hip_runtime.h>

#define HH 1024
#define WW 1024
#define NPIX (HH*WW)
#define NRB 64          // rowblocks per sample (16 rows each)
#define EPSF 1e-8f

__device__ inline float wrsum(float v){ for(int o=32;o;o>>=1) v += __shfl_down(v,o); return v; }
__device__ inline float wrmin(float v){ for(int o=32;o;o>>=1) v = fminf(v,__shfl_down(v,o)); return v; }
__device__ inline float wrmax(float v){ for(int o=32;o;o>>=1) v = fmaxf(v,__shfl_down(v,o)); return v; }

// monotone float<->uint keys for atomicMax
__device__ inline unsigned fkey(float f){
  unsigned u = __float_as_uint(f);
  return (u & 0x80000000u) ? ~u : (u | 0x80000000u);
}
__device__ inline float funkey(unsigned k){
  return (k & 0x80000000u) ? __uint_as_float(k & 0x7FFFFFFFu) : __uint_as_float(~k);
}

// ---- Kernel 0: init atomic col-max array (key 0 < key(any float)) ----
__global__ __launch_bounds__(256) void k_init(unsigned* __restrict__ ColMax){
  int t = threadIdx.x;
  unsigned* p = ColMax + (size_t)blockIdx.x*WW;
  #pragma unroll
  for(int i=0;i<4;i++) p[t + i*256] = 0u;
}

// ---- Kernel 1 (the ONLY full-data pass) ----
// Block = (sample s, rowblock rb of 16 rows). Thread t owns cols 4t..4t+3.
// Outputs: per-(s,row) {max,min,sum}; per-(s,col) atomic max; per-(s,rb) {sabs,cnt,sxx}.
__global__ __launch_bounds__(256) void k_main(const float* __restrict__ x,
    float* __restrict__ RM, float* __restrict__ RMn, float* __restrict__ RS,
    unsigned* __restrict__ ColMax, float* __restrict__ p1){
  int s = blockIdx.x >> 6, rb = blockIdx.x & 63;
  int t = threadIdx.x;
  const float4* xp = (const float4*)(x + (size_t)s*NPIX + (size_t)rb*16*WW);
  float sabs=0.f, cnt=0.f, sxx=0.f;
  float cm4[4]={-INFINITY,-INFINITY,-INFINITY,-INFINITY};
  float rm[16], rn[16], rs[16];
  #pragma unroll
  for(int r=0;r<16;r++){
    float4 v = xp[r*256 + t];
    float a[4]={v.x,v.y,v.z,v.w};
    float rmx=-INFINITY, rmn=INFINITY, rsu=0.f;
    #pragma unroll
    for(int j=0;j<4;j++){
      float xx = a[j];
      rmx = fmaxf(rmx, xx); rmn = fminf(rmn, xx); rsu += xx;
      cm4[j] = fmaxf(cm4[j], xx);
      sxx = fmaf(xx, xx, sxx);
      float e = __expf(fabsf(xx));          // |sigmoid(x)-0.5| = 0.5 - 1/(1+e^{|x|})
      sabs += 0.5f - 1.f/(1.f + e);
      cnt += (xx > 0.f) ? 1.f : 0.f;        // sigmoid(x)>0.5 <=> x>0
    }
    rm[r]=rmx; rn[r]=rmn; rs[r]=rsu;
  }
  // per-sample column max via idempotent atomics (L2-resident, 128KB/sample set)
  #pragma unroll
  for(int j=0;j<4;j++)
    atomicMax(&ColMax[(size_t)s*WW + 4*t + j], fkey(cm4[j]));

  sabs = wrsum(sabs); cnt = wrsum(cnt); sxx = wrsum(sxx);
  __shared__ float sred[3][4];
  __shared__ float rowm[4][16], rown[4][16], rowsu[4][16];
  int wid = t>>6, lane = t&63;
  if(lane==0){ sred[0][wid]=sabs; sred[1][wid]=cnt; sred[2][wid]=sxx; }
  #pragma unroll
  for(int r=0;r<16;r++){
    float a = wrmax(rm[r]), b = wrmin(rn[r]), c = wrsum(rs[r]);
    if(lane==0){ rowm[wid][r]=a; rown[wid][r]=b; rowsu[wid][r]=c; }
  }
  __syncthreads();
  if(t<16){
    size_t ri = (size_t)s*HH + rb*16 + t;
    RM [ri] = fmaxf(fmaxf(rowm[0][t],rowm[1][t]), fmaxf(rowm[2][t],rowm[3][t]));
    RMn[ri] = fminf(fminf(rown[0][t],rown[1][t]), fminf(rown[2][t],rown[3][t]));
    RS [ri] = rowsu[0][t]+rowsu[1][t]+rowsu[2][t]+rowsu[3][t];
  }
  if(t==0){
    float* o = p1 + ((size_t)s*NRB + rb)*3;
    o[0] = sred[0][0]+sred[0][1]+sred[0][2]+sred[0][3];
    o[1] = sred[1][0]+sred[1][1]+sred[1][2]+sred[1][3];
    o[2] = sred[2][0]+sred[2][1]+sred[2][2]+sred[2][3];
  }
}

// ---- Kernel 2: per-sample everything (reads only ~17KB/sample) ----
__global__ __launch_bounds__(256) void k_sample(const float* __restrict__ x,
    const float* __restrict__ RM, const float* __restrict__ RMn,
    const float* __restrict__ RS, const unsigned* __restrict__ ColMax,
    const float* __restrict__ p1, float* __restrict__ lossV, float* __restrict__ valV){
  int s = blockIdx.x, t = threadIdx.x;
  int wid = t>>6, lane = t&63;
  __shared__ float bc[6];
  __shared__ float lred[3][4];
  __shared__ int ext[4];
  // Phase A: vmin/vmax/sx from row arrays; sabs/cnt/sxx from p1
  float vmax=-INFINITY, vmin=INFINITY, sx=0.f;
  #pragma unroll
  for(int i=0;i<4;i++){
    size_t ri = (size_t)s*HH + 4*t + i;
    vmax = fmaxf(vmax, RM[ri]); vmin = fminf(vmin, RMn[ri]); sx += RS[ri];
  }
  vmax = wrmax(vmax); vmin = wrmin(vmin); sx = wrsum(sx);
  if(lane==0){ lred[0][wid]=vmax; lred[1][wid]=vmin; lred[2][wid]=sx; }
  float sabs=0.f, cnt=0.f, sxx=0.f;
  if(t<64){
    const float* o = p1 + ((size_t)s*NRB + t)*3;
    sabs=wrsum(o[0]); cnt=wrsum(o[1]); sxx=wrsum(o[2]);
  }
  if(t==0){ ext[0]=0x7fffffff; ext[1]=-1; ext[2]=0x7fffffff; ext[3]=-1; }
  __syncthreads();
  if(t==0){
    float M = fmaxf(fmaxf(lred[0][0],lred[0][1]), fmaxf(lred[0][2],lred[0][3]));
    float m = fminf(fminf(lred[1][0],lred[1][1]), fminf(lred[1][2],lred[1][3]));
    float X = lred[2][0]+lred[2][1]+lred[2][2]+lred[2][3];
    float lo=m, d=M-m+EPSF, inv=1.f/d;
    float conf = sabs/(float)NPIX, area = cnt/(float)NPIX;
    float w = 0.4f;
    if(conf < 0.3f)  w *= 2.0f;
    if(area < 0.05f) w *= 1.5f;
    if(conf > 0.4f && area > 0.1f) w *= 0.5f;
    bc[0]=lo; bc[1]=inv; bc[2]=lo+0.5f*d; bc[3]=w;
    bc[4]=inv*inv*(sxx - 2.f*lo*X + (float)NPIX*lo*lo);
  }
  __syncthreads();
  float lo=bc[0], inv=bc[1], T=bc[2], w=bc[3], spn2=bc[4];
  // Phase B: extents
  {
    int rlo=0x7fffffff, rhi=-1, clo=0x7fffffff, chi=-1;
    #pragma unroll
    for(int i=0;i<4;i++){
      int r = 4*t+i;
      if(RM[(size_t)s*HH + r] > T){ rlo=min(rlo,r); rhi=max(rhi,r); }
      if(funkey(ColMax[(size_t)s*WW + r]) > T){ clo=min(clo,r); chi=max(chi,r); }
    }
    if(rhi>=0){ atomicMin(&ext[0],rlo); atomicMax(&ext[1],rhi); }
    if(chi>=0){ atomicMin(&ext[2],clo); atomicMax(&ext[3],chi); }
  }
  __syncthreads();
  int r0=ext[0], r1=ext[1], c0=ext[2], c1=ext[3];
  // Phase C: rect sum & min
  float su=0.f, mi=INFINITY;
  if(r1 >= 0){
    if(c0==0 && c1==WW-1){           // full-width fast path (row arrays exact)
      #pragma unroll
      for(int i=0;i<4;i++){
        int r = 4*t+i;
        if(r>=r0 && r<=r1){
          size_t ri = (size_t)s*HH + r;
          su += RS[ri]; mi = fminf(mi, RMn[ri]);
        }
      }
    } else {                          // general fallback: direct x over rect
      for(int r=r0; r<=r1; r++){
        const float* xr = x + (size_t)s*NPIX + (size_t)r*WW;
        for(int c=c0+t; c<=c1; c+=256){ float v=xr[c]; su += v; mi = fminf(mi,v); }
      }
    }
  }
  su = wrsum(su); mi = wrmin(mi);
  __shared__ float l1[4], l2[4];
  if(lane==0){ l1[wid]=su; l2[wid]=mi; }
  __syncthreads();
  if(t==0){
    float S = l1[0]+l1[1]+l1[2]+l1[3];
    float Mn = fminf(fminf(l2[0],l2[1]), fminf(l2[2],l2[3]));
    float loss=0.f, val=0.f;
    if(r1 >= 0){
      float area = (float)((r1-r0+1)*(c1-c0+1));
      val = (Mn <= T) ? 1.f : 0.f;          // exists rect pixel not binary
      float srpn = inv*(S - area*lo);       // sum of pn over rect
      loss = ((spn2 - 2.f*srpn + area)/(float)NPIX) * w * val;
    }
    lossV[s]=loss; valV[s]=val;
  }
}

// ---- Kernel 3: combine over samples (serial, reference order) ----
__global__ __launch_bounds__(64) void k_final(const float* __restrict__ lossV,
    const float* __restrict__ valV, float* __restrict__ out, int B){
  if(threadIdx.x==0){
    float L=0.f, V=0.f;
    for(int s=0; s<B; s++){ L += lossV[s]; V += valV[s]; }
    out[0] = (V > 0.f) ? (L / fmaxf(V, 1.f)) : 0.f;
  }
}

extern "C" void kernel_launch(void* const* d_in, const int* in_sizes, int n_in,
                              void* d_out, int out_size, void* d_ws, size_t ws_size,
                              hipStream_t stream) {
  const float* x = (const float*)d_in[0];
  int B = in_sizes[0] / NPIX;   // 32
  char* ws = (char*)d_ws;
  float*    RM    = (float*)(ws);                       // B*1024*4 = 128 KB
  float*    RMn   = (float*)(ws + 131072);              // 128 KB
  float*    RS    = (float*)(ws + 262144);              // 128 KB
  unsigned* ColMax= (unsigned*)(ws + 393216);           // 128 KB
  float*    p1    = (float*)(ws + 524288);              // B*64*3 = 24 KB
  float*    lossV = (float*)(ws + 557056);              // 128 B
  float*    valV  = (float*)(ws + 557184);              // 128 B
  float*    out   = (float*)d_out;

  k_init  <<<B,     256, 0, stream>>>(ColMax);
  k_main  <<<B*NRB, 256, 0, stream>>>(x, RM, RMn, RS, ColMax, p1);
  k_sample<<<B,     256, 0, stream>>>(x, RM, RMn, RS, ColMax, p1, lossV, valV);
  k_final <<<1,     64,  0, stream>>>(lossV, valV, out, B);
}

// Round 6
// 65.245 us; speedup vs baseline: 1.5570x; 1.0231x over previous
//
#include <hip/hip_runtime.h>

#define HH 1024
#define WW 1024
#define NPIX (HH*WW)
#define NRB 64          // rowblocks per sample (16 rows each)
#define EPSF 1e-8f
#define AGENT __HIP_MEMORY_SCOPE_AGENT

__device__ inline float wrsum(float v){ for(int o=32;o;o>>=1) v += __shfl_down(v,o); return v; }
__device__ inline float wrmin(float v){ for(int o=32;o;o>>=1) v = fminf(v,__shfl_down(v,o)); return v; }
__device__ inline float wrmax(float v){ for(int o=32;o;o>>=1) v = fmaxf(v,__shfl_down(v,o)); return v; }

// ---- Kernel 1 (the ONLY full-data pass) ----
// Block = (sample s, rowblock rb of 16 rows). Thread t owns cols 4t..4t+3.
// Outputs: per-(s,row) {max,min,sum}; per-(s,rb,col) max (plain writes, no atomics);
// per-(s,rb) {sabs,cnt,sxx}. Also zeroes the finalize counter for kernel 2.
__global__ __launch_bounds__(256) void k_main(const float* __restrict__ x,
    float* __restrict__ RM, float* __restrict__ RMn, float* __restrict__ RS,
    float* __restrict__ CM, float* __restrict__ p1, int* __restrict__ ctr){
  int s = blockIdx.x >> 6, rb = blockIdx.x & 63;
  int t = threadIdx.x;
  if(blockIdx.x==0 && t==0) *ctr = 0;
  const float4* xp = (const float4*)(x + (size_t)s*NPIX + (size_t)rb*16*WW);
  float sabs=0.f, cnt=0.f, sxx=0.f;
  float cm4[4]={-INFINITY,-INFINITY,-INFINITY,-INFINITY};
  float rm[16], rn[16], rs[16];
  #pragma unroll
  for(int r=0;r<16;r++){
    float4 v = xp[r*256 + t];
    float a[4]={v.x,v.y,v.z,v.w};
    float rmx=-INFINITY, rmn=INFINITY, rsu=0.f;
    #pragma unroll
    for(int j=0;j<4;j++){
      float xx = a[j];
      rmx = fmaxf(rmx, xx); rmn = fminf(rmn, xx); rsu += xx;
      cm4[j] = fmaxf(cm4[j], xx);
      sxx = fmaf(xx, xx, sxx);
      float e = __expf(fabsf(xx));          // |sigmoid(x)-0.5| = 0.5 - 1/(1+e^{|x|})
      sabs += 0.5f - 1.f/(1.f + e);
      cnt += (xx > 0.f) ? 1.f : 0.f;        // sigmoid(x)>0.5 <=> x>0
    }
    rm[r]=rmx; rn[r]=rmn; rs[r]=rsu;
  }
  // per-(s,rb) column-max partial: plain coalesced float4 store
  *(float4*)(CM + ((size_t)s*NRB + rb)*WW + 4*t) = make_float4(cm4[0],cm4[1],cm4[2],cm4[3]);

  sabs = wrsum(sabs); cnt = wrsum(cnt); sxx = wrsum(sxx);
  __shared__ float sred[3][4];
  __shared__ float rowm[4][16], rown[4][16], rowsu[4][16];
  int wid = t>>6, lane = t&63;
  if(lane==0){ sred[0][wid]=sabs; sred[1][wid]=cnt; sred[2][wid]=sxx; }
  #pragma unroll
  for(int r=0;r<16;r++){
    float a = wrmax(rm[r]), b = wrmin(rn[r]), c = wrsum(rs[r]);
    if(lane==0){ rowm[wid][r]=a; rown[wid][r]=b; rowsu[wid][r]=c; }
  }
  __syncthreads();
  if(t<16){
    size_t ri = (size_t)s*HH + rb*16 + t;
    RM [ri] = fmaxf(fmaxf(rowm[0][t],rowm[1][t]), fmaxf(rowm[2][t],rowm[3][t]));
    RMn[ri] = fminf(fminf(rown[0][t],rown[1][t]), fminf(rown[2][t],rown[3][t]));
    RS [ri] = rowsu[0][t]+rowsu[1][t]+rowsu[2][t]+rowsu[3][t];
  }
  if(t==0){
    float* o = p1 + ((size_t)s*NRB + rb)*3;
    o[0] = sred[0][0]+sred[0][1]+sred[0][2]+sred[0][3];
    o[1] = sred[1][0]+sred[1][1]+sred[1][2]+sred[1][3];
    o[2] = sred[2][0]+sred[2][1]+sred[2][2]+sred[2][3];
  }
}

// ---- Kernel 2: per-sample everything + last-block global combine ----
__global__ __launch_bounds__(256) void k_sample(const float* __restrict__ x,
    const float* __restrict__ RM, const float* __restrict__ RMn,
    const float* __restrict__ RS, const float* __restrict__ CM,
    const float* __restrict__ p1, float* __restrict__ lossV, float* __restrict__ valV,
    int* __restrict__ ctr, float* __restrict__ out, int B){
  int s = blockIdx.x, t = threadIdx.x;
  int wid = t>>6, lane = t&63;
  __shared__ float bc[6];
  __shared__ float lred[3][4];
  __shared__ int ext[4];
  // Phase A: vmin/vmax/sx from row arrays; sabs/cnt/sxx from p1
  float vmax=-INFINITY, vmin=INFINITY, sx=0.f;
  #pragma unroll
  for(int i=0;i<4;i++){
    size_t ri = (size_t)s*HH + 4*t + i;
    vmax = fmaxf(vmax, RM[ri]); vmin = fminf(vmin, RMn[ri]); sx += RS[ri];
  }
  vmax = wrmax(vmax); vmin = wrmin(vmin); sx = wrsum(sx);
  if(lane==0){ lred[0][wid]=vmax; lred[1][wid]=vmin; lred[2][wid]=sx; }
  float sabs=0.f, cnt=0.f, sxx=0.f;
  if(t<64){
    const float* o = p1 + ((size_t)s*NRB + t)*3;
    sabs=wrsum(o[0]); cnt=wrsum(o[1]); sxx=wrsum(o[2]);
  }
  if(t==0){ ext[0]=0x7fffffff; ext[1]=-1; ext[2]=0x7fffffff; ext[3]=-1; }
  __syncthreads();
  if(t==0){
    float M = fmaxf(fmaxf(lred[0][0],lred[0][1]), fmaxf(lred[0][2],lred[0][3]));
    float m = fminf(fminf(lred[1][0],lred[1][1]), fminf(lred[1][2],lred[1][3]));
    float X = lred[2][0]+lred[2][1]+lred[2][2]+lred[2][3];
    float lo=m, d=M-m+EPSF, inv=1.f/d;
    float conf = sabs/(float)NPIX, area = cnt/(float)NPIX;
    float w = 0.4f;
    if(conf < 0.3f)  w *= 2.0f;
    if(area < 0.05f) w *= 1.5f;
    if(conf > 0.4f && area > 0.1f) w *= 0.5f;
    bc[0]=lo; bc[1]=inv; bc[2]=lo+0.5f*d; bc[3]=w;
    bc[4]=inv*inv*(sxx - 2.f*lo*X + (float)NPIX*lo*lo);
  }
  __syncthreads();
  float lo=bc[0], inv=bc[1], T=bc[2], w=bc[3], spn2=bc[4];
  // Phase B: extents. Cols: reduce CM partials over 64 rowblocks (thread t: cols 4t..4t+3)
  {
    const float4* cm = (const float4*)(CM + (size_t)s*NRB*WW) + t;
    float4 mx = cm[0];
    #pragma unroll 8
    for(int rb=1; rb<NRB; rb++){
      float4 v = cm[(size_t)rb*256];
      mx.x=fmaxf(mx.x,v.x); mx.y=fmaxf(mx.y,v.y);
      mx.z=fmaxf(mx.z,v.z); mx.w=fmaxf(mx.w,v.w);
    }
    float a4[4]={mx.x,mx.y,mx.z,mx.w};
    int clo=0x7fffffff, chi=-1, rlo=0x7fffffff, rhi=-1;
    #pragma unroll
    for(int i=0;i<4;i++){
      int c = 4*t+i;
      if(a4[i] > T){ clo=min(clo,c); chi=max(chi,c); }
      if(RM[(size_t)s*HH + c] > T){ rlo=min(rlo,c); rhi=max(rhi,c); }
    }
    if(chi>=0){ atomicMin(&ext[2],clo); atomicMax(&ext[3],chi); }
    if(rhi>=0){ atomicMin(&ext[0],rlo); atomicMax(&ext[1],rhi); }
  }
  __syncthreads();
  int r0=ext[0], r1=ext[1], c0=ext[2], c1=ext[3];
  // Phase C: rect sum & min
  float su=0.f, mi=INFINITY;
  if(r1 >= 0){
    if(c0==0 && c1==WW-1){           // full-width fast path (row arrays exact)
      #pragma unroll
      for(int i=0;i<4;i++){
        int r = 4*t+i;
        if(r>=r0 && r<=r1){
          size_t ri = (size_t)s*HH + r;
          su += RS[ri]; mi = fminf(mi, RMn[ri]);
        }
      }
    } else {                          // general fallback: direct x over rect
      for(int r=r0; r<=r1; r++){
        const float* xr = x + (size_t)s*NPIX + (size_t)r*WW;
        for(int c=c0+t; c<=c1; c+=256){ float v=xr[c]; su += v; mi = fminf(mi,v); }
      }
    }
  }
  su = wrsum(su); mi = wrmin(mi);
  __shared__ float l1[4], l2[4];
  if(lane==0){ l1[wid]=su; l2[wid]=mi; }
  __syncthreads();
  if(t==0){
    float S = l1[0]+l1[1]+l1[2]+l1[3];
    float Mn = fminf(fminf(l2[0],l2[1]), fminf(l2[2],l2[3]));
    float loss=0.f, val=0.f;
    if(r1 >= 0){
      float area = (float)((r1-r0+1)*(c1-c0+1));
      val = (Mn <= T) ? 1.f : 0.f;          // exists rect pixel not binary
      float srpn = inv*(S - area*lo);       // sum of pn over rect
      loss = ((spn2 - 2.f*srpn + area)/(float)NPIX) * w * val;
    }
    lossV[s]=loss; valV[s]=val;
    __threadfence();
    int old = __hip_atomic_fetch_add(ctr, 1, __ATOMIC_ACQ_REL, AGENT);
    if(old == B-1){
      __threadfence();
      float L=0.f, V=0.f;
      for(int ss=0; ss<B; ss++){            // fixed order -> deterministic
        L += __hip_atomic_load(&lossV[ss], __ATOMIC_RELAXED, AGENT);
        V += __hip_atomic_load(&valV[ss],  __ATOMIC_RELAXED, AGENT);
      }
      out[0] = (V > 0.f) ? (L / fmaxf(V, 1.f)) : 0.f;
    }
  }
}

extern "C" void kernel_launch(void* const* d_in, const int* in_sizes, int n_in,
                              void* d_out, int out_size, void* d_ws, size_t ws_size,
                              hipStream_t stream) {
  const float* x = (const float*)d_in[0];
  int B = in_sizes[0] / NPIX;   // 32
  char* ws = (char*)d_ws;
  float* CM    = (float*)(ws);                             // B*64*1024*4 = 8 MB
  float* RM    = (float*)(ws + (size_t)8*1024*1024);       // 128 KB
  float* RMn   = (float*)(ws + (size_t)8*1024*1024 + 131072);
  float* RS    = (float*)(ws + (size_t)8*1024*1024 + 262144);
  float* p1    = (float*)(ws + (size_t)8*1024*1024 + 393216);  // 24 KB
  float* lossV = (float*)(ws + (size_t)8*1024*1024 + 425984);  // 128 B
  float* valV  = (float*)(ws + (size_t)8*1024*1024 + 426112);  // 128 B
  int*   ctr   = (int*)  (ws + (size_t)8*1024*1024 + 426240);  // 4 B
  float* out   = (float*)d_out;

  k_main  <<<B*NRB, 256, 0, stream>>>(x, RM, RMn, RS, CM, p1, ctr);
  k_sample<<<B,     256, 0, stream>>>(x, RM, RMn, RS, CM, p1, lossV, valV, ctr, out, B);
}